// Round 6
// baseline (3028.689 us; speedup 1.0000x reference)
//
#include <hip/hip_runtime.h>
#include <hip/hip_bf16.h>
#include <cmath>

// ---------------------------------------------------------------------------
// MultiHeadMamba6mer: 2-layer Mamba2 + 4 classification heads.
// B=32 L=512 D_MODEL=384 D_INNER=768 D_STATE=64 D_CONV=4 HEADDIM=48 NHEADS=16
// D_IN_PROJ=1680 CONV_DIM=896. Output (32, 38667) FLOAT32 (reference dtype).
// Input float dtype AUTO-DETECTED (fp32 vs bf16) from ln_w (== ones).
// R4: scan LDS chunk staging (Tc=64): 1480 -> 622 us.
// R5 post-mortem: VGPR_Count=52 -> state lived in AGPRs + serialized ds_reads
//     (~2900 cyc/t). R6: __launch_bounds__(64,1) for full VGPR budget +
//     batch-load B/C quads into registers, float4 staging.
// ---------------------------------------------------------------------------

#define B_SZ 32
#define L_SZ 512
#define DMODEL 384
#define DINNER 768
#define DSTATE 64
#define HEADDIM 48
#define NHEADS 16
#define DINPROJ 1680
#define CONVDIM 896
#define ROWS (B_SZ * L_SZ)          // 16384
#define OUT_STRIDE 38667
#define TC 64                        // scan chunk length

typedef __hip_bfloat16 bf16;

__device__ __forceinline__ float ldw(const void* p, size_t i, bool isb) {
    if (isb) return __bfloat162float(((const bf16*)p)[i]);
    else     return ((const float*)p)[i];
}

// ---------------- dtype detect: flag = 1 if bf16, 0 if fp32 ----------------
__global__ void detect_kernel(const void* __restrict__ ln_w, int* __restrict__ flag) {
    unsigned u = *(const unsigned*)ln_w;
    *flag = (u == 0x3F800000u) ? 0 : 1;
}

// ---------------- embed ----------------
__global__ void embed_kernel(const int* __restrict__ tok,
                             const void* __restrict__ emb,
                             float* __restrict__ resid,
                             const int* __restrict__ dflag) {
    bool isb = (*dflag != 0);
    int r = blockIdx.x, d = threadIdx.x;                  // block 384
    resid[(size_t)r * DMODEL + d] = ldw(emb, (size_t)tok[r] * DMODEL + d, isb);
}

// ---------------- layernorm (one wave per row) ----------------
__global__ void layernorm_off(const float* __restrict__ x,
                              const void* __restrict__ w,
                              const void* __restrict__ b, long off,
                              float* __restrict__ out, int D,
                              const int* __restrict__ dflag) {
    bool isb = (*dflag != 0);
    int row = blockIdx.x, lane = threadIdx.x;             // block 64
    const float* xr = x + (size_t)row * D;
    float s = 0.f, s2 = 0.f;
    for (int d = lane; d < D; d += 64) { float v = xr[d]; s += v; s2 += v * v; }
    #pragma unroll
    for (int o = 32; o; o >>= 1) { s += __shfl_xor(s, o); s2 += __shfl_xor(s2, o); }
    float mu = s / D;
    float var = s2 / D - mu * mu;
    float rinv = rsqrtf(var + 1e-5f);
    for (int d = lane; d < D; d += 64)
        out[(size_t)row * D + d] =
            (xr[d] - mu) * rinv * ldw(w, off + d, isb) + ldw(b, off + d, isb);
}

// ---------------- tiled fp32 GEMM: C[M,N] = A[M,K](lda) * W[K,N] (+Cadd) ------
__global__ void gemm_off(const float* __restrict__ A, int lda,
                         const void* __restrict__ Bw, long boff,
                         float* __restrict__ C, int ldc,
                         const float* __restrict__ Cadd,
                         int M, int N, int K,
                         const int* __restrict__ dflag) {
    bool isb = (*dflag != 0);
    __shared__ float As[16][68];
    __shared__ float Bs[16][68];
    const int bm = blockIdx.y * 64;
    const int bn = blockIdx.x * 64;
    const int tid = threadIdx.x;
    const int tx = tid & 15;
    const int ty = tid >> 4;
    float acc[4][4] = {};
    for (int k0 = 0; k0 < K; k0 += 16) {
        #pragma unroll
        for (int i = 0; i < 4; ++i) {
            int e = tid + 256 * i;
            int m = e >> 4, k = e & 15;
            As[k][m] = A[(size_t)(bm + m) * lda + k0 + k];
            int n = e & 63, kk = e >> 6;
            int gn = bn + n;
            Bs[kk][n] = (gn < N) ? ldw(Bw, boff + (size_t)(k0 + kk) * N + gn, isb) : 0.f;
        }
        __syncthreads();
        #pragma unroll
        for (int k = 0; k < 16; ++k) {
            float4 av = *(const float4*)&As[k][ty * 4];
            float4 bv = *(const float4*)&Bs[k][tx * 4];
            float a[4] = {av.x, av.y, av.z, av.w};
            float b4[4] = {bv.x, bv.y, bv.z, bv.w};
            #pragma unroll
            for (int i = 0; i < 4; ++i)
                #pragma unroll
                for (int j = 0; j < 4; ++j)
                    acc[i][j] += a[i] * b4[j];
        }
        __syncthreads();
    }
    #pragma unroll
    for (int i = 0; i < 4; ++i) {
        int m = bm + ty * 4 + i;
        int n = bn + tx * 4;
        if (n < N) {
            size_t idx = (size_t)m * ldc + n;
            float4 v = make_float4(acc[i][0], acc[i][1], acc[i][2], acc[i][3]);
            if (Cadd) {
                float4 c0 = *(const float4*)&Cadd[idx];
                v.x += c0.x; v.y += c0.y; v.z += c0.z; v.w += c0.w;
            }
            *(float4*)&C[idx] = v;
        }
    }
}

// ---------------- causal depthwise conv(4) + bias + SiLU ----------------
__global__ void conv_silu_off(const float* __restrict__ zx,
                              const void* __restrict__ cw,
                              const void* __restrict__ cb,
                              long cwoff, long cboff,
                              float* __restrict__ out,
                              const int* __restrict__ dflag) {
    bool isb = (*dflag != 0);
    int c = blockIdx.x * 128 + threadIdx.x;               // < 896 (7*128)
    int r = blockIdx.y;                                   // b*512 + l
    int l = r & (L_SZ - 1);
    float acc = ldw(cb, cboff + c, isb);
    #pragma unroll
    for (int k = 0; k < 4; ++k) {
        int lsrc = l + k - 3;
        if (lsrc >= 0)
            acc += zx[(size_t)(r + k - 3) * DINPROJ + DINNER + c] *
                   ldw(cw, cwoff + c * 4 + k, isb);
    }
    out[(size_t)r * CONVDIM + c] = acc / (1.f + expf(-acc));
}

// ---------------- dt = softplus(raw + bias); dA = exp(-exp(alog)*dt) ----------
__global__ void dt_off(const float* __restrict__ zx,
                       const void* __restrict__ dtb,
                       const void* __restrict__ alog, long hoff,
                       float* __restrict__ dtout, float* __restrict__ dAout,
                       const int* __restrict__ dflag) {
    bool isb = (*dflag != 0);
    int idx = blockIdx.x * 256 + threadIdx.x;             // < ROWS*NHEADS
    int r = idx >> 4, h = idx & 15;
    float x = zx[(size_t)r * DINPROJ + (DINPROJ - NHEADS) + h] + ldw(dtb, hoff + h, isb);
    float sp = (x > 20.f) ? x : log1pf(expf(x));
    float A = expf(ldw(alog, hoff + h, isb));
    dtout[idx] = sp;
    dAout[idx] = expf(-A * sp);
}

// ---------------- SSM scan, LDS chunk-staged, 1 wave/(b,h), full VGPR budget --
// Lane p holds state[p][0..63] (64 VGPRs). Per TC=64 chunk: float4-stage
// x/B/C + dt/dA, then serial recurrence reading B/C quads batch-wise into
// registers (16+16 b128 reads issued back-to-back, then FMA).
__global__ __launch_bounds__(64, 1)
void scan_off(float* __restrict__ conv,
              const float* __restrict__ dtg,
              const float* __restrict__ dAg,
              const void* __restrict__ Dsk, long hoff,
              const int* __restrict__ dflag) {
    bool isb = (*dflag != 0);
    int b = blockIdx.x >> 4, h = blockIdx.x & 15;
    int lane = threadIdx.x;                               // 64 (one wave)
    __shared__ __align__(16) float4 sX4[TC][12];          // 12 KB
    __shared__ __align__(16) float4 sB4[TC][16];          // 16 KB
    __shared__ __align__(16) float4 sC4[TC][16];          // 16 KB
    __shared__ float sdt[TC];
    __shared__ float sdA[TC];
    float st[64];
    #pragma unroll
    for (int n = 0; n < 64; ++n) st[n] = 0.f;
    float dskip = ldw(Dsk, hoff + h, isb);
    float* base = conv + (size_t)b * L_SZ * CONVDIM;

    for (int c0 = 0; c0 < L_SZ; c0 += TC) {
        // ---- stage chunk (float4): lane role split over 44 quads/row ----
        sdt[lane] = dtg[((size_t)(b * L_SZ + c0 + lane)) * NHEADS + h];
        sdA[lane] = dAg[((size_t)(b * L_SZ + c0 + lane)) * NHEADS + h];
        for (int tt = 0; tt < TC; ++tt) {
            const float4* row4 = (const float4*)(base + (size_t)(c0 + tt) * CONVDIM);
            if (lane < 16)       sB4[tt][lane]      = row4[192 + lane];
            else if (lane < 32)  sC4[tt][lane - 16] = row4[208 + (lane - 16)];
            else if (lane < 44)  sX4[tt][lane - 32] = row4[h * 12 + (lane - 32)];
        }
        __syncthreads();
        // ---- serial recurrence out of LDS ----
        for (int tt = 0; tt < TC; ++tt) {
            float xv = (lane < HEADDIM) ? ((const float*)&sX4[tt][0])[lane] : 0.f;
            float dAv = sdA[tt];
            float coef = sdt[tt] * xv;
            float4 bq[16], cq[16];
            #pragma unroll
            for (int q = 0; q < 16; ++q) { bq[q] = sB4[tt][q]; cq[q] = sC4[tt][q]; }
            float a0 = 0.f, a1 = 0.f, a2 = 0.f, a3 = 0.f;
            #pragma unroll
            for (int q = 0; q < 16; ++q) {
                st[4*q + 0] = st[4*q + 0] * dAv + coef * bq[q].x; a0 += st[4*q + 0] * cq[q].x;
                st[4*q + 1] = st[4*q + 1] * dAv + coef * bq[q].y; a1 += st[4*q + 1] * cq[q].y;
                st[4*q + 2] = st[4*q + 2] * dAv + coef * bq[q].z; a2 += st[4*q + 2] * cq[q].z;
                st[4*q + 3] = st[4*q + 3] * dAv + coef * bq[q].w; a3 += st[4*q + 3] * cq[q].w;
            }
            float y = (a0 + a1) + (a2 + a3) + dskip * xv;
            if (lane < HEADDIM)
                base[(size_t)(c0 + tt) * CONVDIM + h * HEADDIM + lane] = y;
        }
        __syncthreads();                                  // LDS reuse guard
    }
}

// ---------------- gated RMSNorm ----------------
__global__ void gated_off(float* __restrict__ y,          // conv buf rows (896)
                          const float* __restrict__ zx,
                          const void* __restrict__ gw, long goff,
                          const int* __restrict__ dflag) {
    bool isb = (*dflag != 0);
    int row = blockIdx.x, tid = threadIdx.x;              // block 256
    float* yr = y + (size_t)row * CONVDIM;
    const float* zr = zx + (size_t)row * DINPROJ;
    float g[3], s2 = 0.f;
    #pragma unroll
    for (int i = 0; i < 3; ++i) {
        int d = tid + 256 * i;
        float z = zr[d];
        float sz = z / (1.f + expf(-z));
        float v = yr[d] * sz;
        g[i] = v; s2 += v * v;
    }
    #pragma unroll
    for (int o = 32; o; o >>= 1) s2 += __shfl_xor(s2, o);
    __shared__ float red[4];
    if ((tid & 63) == 0) red[tid >> 6] = s2;
    __syncthreads();
    s2 = red[0] + red[1] + red[2] + red[3];
    float rinv = rsqrtf(s2 / (float)DINNER + 1e-5f);
    #pragma unroll
    for (int i = 0; i < 3; ++i) {
        int d = tid + 256 * i;
        yr[d] = g[i] * rinv * ldw(gw, goff + d, isb);
    }
}

// ---------------- mean over L ----------------
__global__ void pool_kernel(const float* __restrict__ h, float* __restrict__ feat0) {
    int b = blockIdx.x, d = threadIdx.x;                  // block 384
    float s = 0.f;
    for (int l = 0; l < L_SZ; ++l) s += h[((size_t)b * L_SZ + l) * DMODEL + d];
    feat0[b * DMODEL + d] = s * (1.f / L_SZ);
}

// ---------------- head GEMV (fp32 output) ----------------
__global__ void head_kernel(const float* __restrict__ feat,
                            const void* __restrict__ W,
                            const void* __restrict__ bias,
                            float* __restrict__ out, int N, int off,
                            const int* __restrict__ dflag) {
    bool isb = (*dflag != 0);
    __shared__ float sf[DMODEL];
    int b = blockIdx.y;
    for (int i = threadIdx.x; i < DMODEL; i += 256) sf[i] = feat[b * DMODEL + i];
    __syncthreads();
    int j = blockIdx.x * 256 + threadIdx.x;
    if (j < N) {
        float acc = ldw(bias, j, isb);
        if (isb) {
            const bf16* Wb = (const bf16*)W;
            for (int k = 0; k < DMODEL; ++k)
                acc += sf[k] * __bfloat162float(Wb[(size_t)k * N + j]);
        } else {
            const float* Wf = (const float*)W;
            for (int k = 0; k < DMODEL; ++k)
                acc += sf[k] * Wf[(size_t)k * N + j];
        }
        out[(size_t)b * OUT_STRIDE + off + j] = acc;
    }
}

// ---------------------------------------------------------------------------
extern "C" void kernel_launch(void* const* d_in, const int* in_sizes, int n_in,
                              void* d_out, int out_size, void* d_ws, size_t ws_size,
                              hipStream_t stream) {
    const int*  tokens   = (const int*)d_in[0];
    const void* emb      = d_in[1];
    const void* ln_w     = d_in[2];
    const void* ln_b     = d_in[3];
    const void* in_proj  = d_in[4];
    const void* conv_w   = d_in[5];
    const void* conv_b   = d_in[6];
    const void* dt_bias  = d_in[7];
    const void* A_log    = d_in[8];
    const void* Dp       = d_in[9];
    const void* gnorm_w  = d_in[10];
    const void* out_proj = d_in[11];
    const void* normf_w  = d_in[12];
    const void* normf_b  = d_in[13];
    const void* pln_w    = d_in[14];
    const void* pln_b    = d_in[15];
    const void* order_w  = d_in[16];
    const void* order_b  = d_in[17];
    const void* family_w = d_in[18];
    const void* family_b = d_in[19];
    const void* genus_w  = d_in[20];
    const void* genus_b  = d_in[21];
    const void* species_w= d_in[22];
    const void* species_b= d_in[23];
    float* out = (float*)d_out;

    // fp32 workspace layout (~221 MB)
    float* ws    = (float*)d_ws;
    float* resid = ws;                                   // 16384*384
    float* hbuf  = resid + (size_t)ROWS * DMODEL;        // 16384*384
    float* zx    = hbuf  + (size_t)ROWS * DMODEL;        // 16384*1680
    float* convb = zx    + (size_t)ROWS * DINPROJ;       // 16384*896
    float* dtb_  = convb + (size_t)ROWS * CONVDIM;       // 16384*16
    float* dAb   = dtb_  + (size_t)ROWS * NHEADS;        // 16384*16
    float* feat0 = dAb   + (size_t)ROWS * NHEADS;        // 32*384
    float* feat  = feat0 + (size_t)B_SZ * DMODEL;        // 32*384
    int*   dflag = (int*)(feat + (size_t)B_SZ * DMODEL);

    detect_kernel<<<1, 1, 0, stream>>>(ln_w, dflag);
    embed_kernel<<<ROWS, DMODEL, 0, stream>>>(tokens, emb, resid, dflag);

    for (int l = 0; l < 2; ++l) {
        layernorm_off<<<ROWS, 64, 0, stream>>>(resid, ln_w, ln_b,
            (long)l * DMODEL, hbuf, DMODEL, dflag);
        // zxbcdt = h @ W_in   (16384 x 384 -> 1680)
        gemm_off<<<dim3((DINPROJ + 63) / 64, ROWS / 64), 256, 0, stream>>>(
            hbuf, DMODEL, in_proj, (long)l * DMODEL * DINPROJ,
            zx, DINPROJ, nullptr, ROWS, DINPROJ, DMODEL, dflag);
        conv_silu_off<<<dim3(7, ROWS), 128, 0, stream>>>(
            zx, conv_w, conv_b, (long)l * CONVDIM * 4, (long)l * CONVDIM,
            convb, dflag);
        dt_off<<<(ROWS * NHEADS) / 256, 256, 0, stream>>>(
            zx, dt_bias, A_log, (long)l * NHEADS, dtb_, dAb, dflag);
        scan_off<<<B_SZ * NHEADS, 64, 0, stream>>>(convb, dtb_, dAb, Dp,
            (long)l * NHEADS, dflag);
        gated_off<<<ROWS, 256, 0, stream>>>(convb, zx, gnorm_w,
            (long)l * DINNER, dflag);
        // resid += y @ W_out  (16384 x 768 -> 384), y rows strided by 896
        gemm_off<<<dim3(DMODEL / 64, ROWS / 64), 256, 0, stream>>>(
            convb, CONVDIM, out_proj, (long)l * DINNER * DMODEL,
            resid, DMODEL, resid, ROWS, DMODEL, DINNER, dflag);
    }

    layernorm_off<<<ROWS, 64, 0, stream>>>(resid, normf_w, normf_b, 0L,
                                           hbuf, DMODEL, dflag);
    pool_kernel<<<B_SZ, DMODEL, 0, stream>>>(hbuf, feat0);
    layernorm_off<<<B_SZ, 64, 0, stream>>>(feat0, pln_w, pln_b, 0L,
                                           feat, DMODEL, dflag);

    head_kernel<<<dim3(1, B_SZ), 256, 0, stream>>>(feat, order_w, order_b, out, 60, 0, dflag);
    head_kernel<<<dim3(2, B_SZ), 256, 0, stream>>>(feat, family_w, family_b, out, 427, 60, dflag);
    head_kernel<<<dim3(56, B_SZ), 256, 0, stream>>>(feat, genus_w, genus_b, out, 14216, 487, dflag);
    head_kernel<<<dim3(94, B_SZ), 256, 0, stream>>>(feat, species_w, species_b, out, 23964, 14703, dflag);
}

// Round 7
// 2647.966 us; speedup vs baseline: 1.1438x; 1.1438x over previous
//
#include <hip/hip_runtime.h>
#include <hip/hip_bf16.h>
#include <cmath>

// ---------------------------------------------------------------------------
// MultiHeadMamba6mer: 2-layer Mamba2 + 4 classification heads.
// B=32 L=512 D_MODEL=384 D_INNER=768 D_STATE=64 D_CONV=4 HEADDIM=48 NHEADS=16
// D_IN_PROJ=1680 CONV_DIM=896. Output (32, 38667) FLOAT32 (reference dtype).
// Input float dtype AUTO-DETECTED (fp32 vs bf16) from ln_w (== ones).
// R4: scan LDS chunk staging: 1480 -> 622 us. R5/R6: ILP attempts lost to the
//     register allocator (VGPR 52 / 132, st in AGPRs); structural issue is
//     TLP: 512 single-wave blocks = 2 waves/CU.
// R7: chunked PARALLEL scan: L=512 -> 4 chunks of 128, 3 phases, 2048 blocks
//     (8 waves/CU). S_end/prefix stored in dead hbuf region (zero new ws).
//     B/C read as uniform global loads (off the LDS pipe); dt/dA broadcast
//     from VGPRs via shfl; no LDS in scan kernels at all.
// ---------------------------------------------------------------------------

#define B_SZ 32
#define L_SZ 512
#define DMODEL 384
#define DINNER 768
#define DSTATE 64
#define HEADDIM 48
#define NHEADS 16
#define DINPROJ 1680
#define CONVDIM 896
#define ROWS (B_SZ * L_SZ)          // 16384
#define OUT_STRIDE 38667
#define NCH 4                        // scan chunks
#define CHL (L_SZ / NCH)             // 128 timesteps per chunk

typedef __hip_bfloat16 bf16;

__device__ __forceinline__ float ldw(const void* p, size_t i, bool isb) {
    if (isb) return __bfloat162float(((const bf16*)p)[i]);
    else     return ((const float*)p)[i];
}

// ---------------- dtype detect: flag = 1 if bf16, 0 if fp32 ----------------
__global__ void detect_kernel(const void* __restrict__ ln_w, int* __restrict__ flag) {
    unsigned u = *(const unsigned*)ln_w;
    *flag = (u == 0x3F800000u) ? 0 : 1;
}

// ---------------- embed ----------------
__global__ void embed_kernel(const int* __restrict__ tok,
                             const void* __restrict__ emb,
                             float* __restrict__ resid,
                             const int* __restrict__ dflag) {
    bool isb = (*dflag != 0);
    int r = blockIdx.x, d = threadIdx.x;                  // block 384
    resid[(size_t)r * DMODEL + d] = ldw(emb, (size_t)tok[r] * DMODEL + d, isb);
}

// ---------------- layernorm (one wave per row) ----------------
__global__ void layernorm_off(const float* __restrict__ x,
                              const void* __restrict__ w,
                              const void* __restrict__ b, long off,
                              float* __restrict__ out, int D,
                              const int* __restrict__ dflag) {
    bool isb = (*dflag != 0);
    int row = blockIdx.x, lane = threadIdx.x;             // block 64
    const float* xr = x + (size_t)row * D;
    float s = 0.f, s2 = 0.f;
    for (int d = lane; d < D; d += 64) { float v = xr[d]; s += v; s2 += v * v; }
    #pragma unroll
    for (int o = 32; o; o >>= 1) { s += __shfl_xor(s, o); s2 += __shfl_xor(s2, o); }
    float mu = s / D;
    float var = s2 / D - mu * mu;
    float rinv = rsqrtf(var + 1e-5f);
    for (int d = lane; d < D; d += 64)
        out[(size_t)row * D + d] =
            (xr[d] - mu) * rinv * ldw(w, off + d, isb) + ldw(b, off + d, isb);
}

// ---------------- tiled fp32 GEMM: C[M,N] = A[M,K](lda) * W[K,N] (+Cadd) ------
__global__ void gemm_off(const float* __restrict__ A, int lda,
                         const void* __restrict__ Bw, long boff,
                         float* __restrict__ C, int ldc,
                         const float* __restrict__ Cadd,
                         int M, int N, int K,
                         const int* __restrict__ dflag) {
    bool isb = (*dflag != 0);
    __shared__ float As[16][68];
    __shared__ float Bs[16][68];
    const int bm = blockIdx.y * 64;
    const int bn = blockIdx.x * 64;
    const int tid = threadIdx.x;
    const int tx = tid & 15;
    const int ty = tid >> 4;
    float acc[4][4] = {};
    for (int k0 = 0; k0 < K; k0 += 16) {
        #pragma unroll
        for (int i = 0; i < 4; ++i) {
            int e = tid + 256 * i;
            int m = e >> 4, k = e & 15;
            As[k][m] = A[(size_t)(bm + m) * lda + k0 + k];
            int n = e & 63, kk = e >> 6;
            int gn = bn + n;
            Bs[kk][n] = (gn < N) ? ldw(Bw, boff + (size_t)(k0 + kk) * N + gn, isb) : 0.f;
        }
        __syncthreads();
        #pragma unroll
        for (int k = 0; k < 16; ++k) {
            float4 av = *(const float4*)&As[k][ty * 4];
            float4 bv = *(const float4*)&Bs[k][tx * 4];
            float a[4] = {av.x, av.y, av.z, av.w};
            float b4[4] = {bv.x, bv.y, bv.z, bv.w};
            #pragma unroll
            for (int i = 0; i < 4; ++i)
                #pragma unroll
                for (int j = 0; j < 4; ++j)
                    acc[i][j] += a[i] * b4[j];
        }
        __syncthreads();
    }
    #pragma unroll
    for (int i = 0; i < 4; ++i) {
        int m = bm + ty * 4 + i;
        int n = bn + tx * 4;
        if (n < N) {
            size_t idx = (size_t)m * ldc + n;
            float4 v = make_float4(acc[i][0], acc[i][1], acc[i][2], acc[i][3]);
            if (Cadd) {
                float4 c0 = *(const float4*)&Cadd[idx];
                v.x += c0.x; v.y += c0.y; v.z += c0.z; v.w += c0.w;
            }
            *(float4*)&C[idx] = v;
        }
    }
}

// ---------------- causal depthwise conv(4) + bias + SiLU ----------------
__global__ void conv_silu_off(const float* __restrict__ zx,
                              const void* __restrict__ cw,
                              const void* __restrict__ cb,
                              long cwoff, long cboff,
                              float* __restrict__ out,
                              const int* __restrict__ dflag) {
    bool isb = (*dflag != 0);
    int c = blockIdx.x * 128 + threadIdx.x;               // < 896 (7*128)
    int r = blockIdx.y;                                   // b*512 + l
    int l = r & (L_SZ - 1);
    float acc = ldw(cb, cboff + c, isb);
    #pragma unroll
    for (int k = 0; k < 4; ++k) {
        int lsrc = l + k - 3;
        if (lsrc >= 0)
            acc += zx[(size_t)(r + k - 3) * DINPROJ + DINNER + c] *
                   ldw(cw, cwoff + c * 4 + k, isb);
    }
    out[(size_t)r * CONVDIM + c] = acc / (1.f + expf(-acc));
}

// ---------------- dt = softplus(raw + bias); dA = exp(-exp(alog)*dt) ----------
__global__ void dt_off(const float* __restrict__ zx,
                       const void* __restrict__ dtb,
                       const void* __restrict__ alog, long hoff,
                       float* __restrict__ dtout, float* __restrict__ dAout,
                       const int* __restrict__ dflag) {
    bool isb = (*dflag != 0);
    int idx = blockIdx.x * 256 + threadIdx.x;             // < ROWS*NHEADS
    int r = idx >> 4, h = idx & 15;
    float x = zx[(size_t)r * DINPROJ + (DINPROJ - NHEADS) + h] + ldw(dtb, hoff + h, isb);
    float sp = (x > 20.f) ? x : log1pf(expf(x));
    float A = expf(ldw(alog, hoff + h, isb));
    dtout[idx] = sp;
    dAout[idx] = expf(-A * sp);
}

// ============ chunked parallel SSM scan ============
// Grid 2048 = (b, h, chunk); block = 1 wave. Lane p<48 holds state[p][0..63].
// Send slot s = blockIdx.x = b*64 + h*4 + c, 3072 floats each (in dead hbuf).

// Phase 1: local scan from zero state; write S_end and P = prod(dA).
__global__ __launch_bounds__(64, 2)
void scan_p1(const float* __restrict__ conv,
             const float* __restrict__ dtg,
             const float* __restrict__ dAg,
             float* __restrict__ Send, float* __restrict__ Pbuf) {
    int c = blockIdx.x & (NCH - 1);
    int h = (blockIdx.x >> 2) & 15;
    int b = blockIdx.x >> 6;
    int lane = threadIdx.x;
    const float* base = conv + (size_t)b * L_SZ * CONVDIM;
    int t0 = c * CHL;
    // preload dt/dA for the whole chunk: lane holds t0+lane and t0+64+lane
    size_t ri0 = ((size_t)(b * L_SZ + t0 + lane)) * NHEADS + h;
    size_t ri1 = ((size_t)(b * L_SZ + t0 + 64 + lane)) * NHEADS + h;
    float vdt0 = dtg[ri0], vdt1 = dtg[ri1];
    float vdA0 = dAg[ri0], vdA1 = dAg[ri1];
    float st[64];
    #pragma unroll
    for (int n = 0; n < 64; ++n) st[n] = 0.f;
    float aprod = 1.f;
    float xv_next = (lane < HEADDIM) ? base[(size_t)t0 * CONVDIM + h * HEADDIM + lane] : 0.f;
    for (int tt = 0; tt < CHL; ++tt) {
        int t = t0 + tt;
        float xv = xv_next;
        if (tt + 1 < CHL)
            xv_next = (lane < HEADDIM) ? base[(size_t)(t + 1) * CONVDIM + h * HEADDIM + lane] : 0.f;
        float dtv = __shfl(tt < 64 ? vdt0 : vdt1, tt & 63);
        float dAv = __shfl(tt < 64 ? vdA0 : vdA1, tt & 63);
        float coef = dtv * xv;
        aprod *= dAv;
        const float4* B4 = (const float4*)(base + (size_t)t * CONVDIM + DINNER);
        #pragma unroll
        for (int q = 0; q < 16; ++q) {
            float4 Bq = B4[q];                            // uniform address
            st[4*q + 0] = st[4*q + 0] * dAv + coef * Bq.x;
            st[4*q + 1] = st[4*q + 1] * dAv + coef * Bq.y;
            st[4*q + 2] = st[4*q + 2] * dAv + coef * Bq.z;
            st[4*q + 3] = st[4*q + 3] * dAv + coef * Bq.w;
        }
    }
    if (lane < HEADDIM) {
        float4* dst = (float4*)(Send + (size_t)blockIdx.x * 3072 + lane * 64);
        #pragma unroll
        for (int q = 0; q < 16; ++q)
            dst[q] = make_float4(st[4*q], st[4*q+1], st[4*q+2], st[4*q+3]);
    }
    if (lane == 0) Pbuf[blockIdx.x] = aprod;
}

// Phase 2: per (b,h): sequential prefix over chunks (elementwise, coalesced).
// After: slot c holds the prefix state for chunk c+1.
__global__ void scan_p2(float* __restrict__ Send, const float* __restrict__ Pbuf) {
    int bh = blockIdx.x;                                  // 512 blocks
    int lane = threadIdx.x;                               // 64
    float4 S[12];
    #pragma unroll
    for (int q = 0; q < 12; ++q) S[q] = make_float4(0.f, 0.f, 0.f, 0.f);
    for (int c = 0; c < NCH - 1; ++c) {
        float4* slot = (float4*)(Send + ((size_t)bh * NCH + c) * 3072);
        float P = Pbuf[bh * NCH + c];
        #pragma unroll
        for (int q = 0; q < 12; ++q) {
            float4 L = slot[lane + 64 * q];
            S[q].x = S[q].x * P + L.x;
            S[q].y = S[q].y * P + L.y;
            S[q].z = S[q].z * P + L.z;
            S[q].w = S[q].w * P + L.w;
            slot[lane + 64 * q] = S[q];
        }
    }
}

// Phase 3: re-run recurrence with injected prefix state; emit y in place.
__global__ __launch_bounds__(64, 2)
void scan_p3(float* __restrict__ conv,
             const float* __restrict__ dtg,
             const float* __restrict__ dAg,
             const void* __restrict__ Dsk, long hoff,
             const float* __restrict__ Send,
             const int* __restrict__ dflag) {
    bool isb = (*dflag != 0);
    int c = blockIdx.x & (NCH - 1);
    int h = (blockIdx.x >> 2) & 15;
    int b = blockIdx.x >> 6;
    int lane = threadIdx.x;
    float* base = conv + (size_t)b * L_SZ * CONVDIM;
    int t0 = c * CHL;
    size_t ri0 = ((size_t)(b * L_SZ + t0 + lane)) * NHEADS + h;
    size_t ri1 = ((size_t)(b * L_SZ + t0 + 64 + lane)) * NHEADS + h;
    float vdt0 = dtg[ri0], vdt1 = dtg[ri1];
    float vdA0 = dAg[ri0], vdA1 = dAg[ri1];
    float dskip = ldw(Dsk, hoff + h, isb);
    float st[64];
    if (c == 0) {
        #pragma unroll
        for (int n = 0; n < 64; ++n) st[n] = 0.f;
    } else {
        const float4* pre = (const float4*)(Send + ((size_t)blockIdx.x - 1) * 3072);
        if (lane < HEADDIM) {
            #pragma unroll
            for (int q = 0; q < 16; ++q) {
                float4 v = pre[lane * 16 + q];
                st[4*q] = v.x; st[4*q+1] = v.y; st[4*q+2] = v.z; st[4*q+3] = v.w;
            }
        } else {
            #pragma unroll
            for (int n = 0; n < 64; ++n) st[n] = 0.f;
        }
    }
    float xv_next = (lane < HEADDIM) ? base[(size_t)t0 * CONVDIM + h * HEADDIM + lane] : 0.f;
    for (int tt = 0; tt < CHL; ++tt) {
        int t = t0 + tt;
        float xv = xv_next;
        if (tt + 1 < CHL)
            xv_next = (lane < HEADDIM) ? base[(size_t)(t + 1) * CONVDIM + h * HEADDIM + lane] : 0.f;
        float dtv = __shfl(tt < 64 ? vdt0 : vdt1, tt & 63);
        float dAv = __shfl(tt < 64 ? vdA0 : vdA1, tt & 63);
        float coef = dtv * xv;
        const float4* B4 = (const float4*)(base + (size_t)t * CONVDIM + DINNER);
        const float4* C4 = (const float4*)(base + (size_t)t * CONVDIM + DINNER + DSTATE);
        float a0 = 0.f, a1 = 0.f, a2 = 0.f, a3 = 0.f;
        #pragma unroll
        for (int q = 0; q < 16; ++q) {
            float4 Bq = B4[q];
            float4 Cq = C4[q];
            st[4*q + 0] = st[4*q + 0] * dAv + coef * Bq.x; a0 += st[4*q + 0] * Cq.x;
            st[4*q + 1] = st[4*q + 1] * dAv + coef * Bq.y; a1 += st[4*q + 1] * Cq.y;
            st[4*q + 2] = st[4*q + 2] * dAv + coef * Bq.z; a2 += st[4*q + 2] * Cq.z;
            st[4*q + 3] = st[4*q + 3] * dAv + coef * Bq.w; a3 += st[4*q + 3] * Cq.w;
        }
        float y = (a0 + a1) + (a2 + a3) + dskip * xv;
        if (lane < HEADDIM)
            base[(size_t)t * CONVDIM + h * HEADDIM + lane] = y;
    }
}

// ---------------- gated RMSNorm ----------------
__global__ void gated_off(float* __restrict__ y,          // conv buf rows (896)
                          const float* __restrict__ zx,
                          const void* __restrict__ gw, long goff,
                          const int* __restrict__ dflag) {
    bool isb = (*dflag != 0);
    int row = blockIdx.x, tid = threadIdx.x;              // block 256
    float* yr = y + (size_t)row * CONVDIM;
    const float* zr = zx + (size_t)row * DINPROJ;
    float g[3], s2 = 0.f;
    #pragma unroll
    for (int i = 0; i < 3; ++i) {
        int d = tid + 256 * i;
        float z = zr[d];
        float sz = z / (1.f + expf(-z));
        float v = yr[d] * sz;
        g[i] = v; s2 += v * v;
    }
    #pragma unroll
    for (int o = 32; o; o >>= 1) s2 += __shfl_xor(s2, o);
    __shared__ float red[4];
    if ((tid & 63) == 0) red[tid >> 6] = s2;
    __syncthreads();
    s2 = red[0] + red[1] + red[2] + red[3];
    float rinv = rsqrtf(s2 / (float)DINNER + 1e-5f);
    #pragma unroll
    for (int i = 0; i < 3; ++i) {
        int d = tid + 256 * i;
        yr[d] = g[i] * rinv * ldw(gw, goff + d, isb);
    }
}

// ---------------- mean over L ----------------
__global__ void pool_kernel(const float* __restrict__ h, float* __restrict__ feat0) {
    int b = blockIdx.x, d = threadIdx.x;                  // block 384
    float s = 0.f;
    for (int l = 0; l < L_SZ; ++l) s += h[((size_t)b * L_SZ + l) * DMODEL + d];
    feat0[b * DMODEL + d] = s * (1.f / L_SZ);
}

// ---------------- head GEMV (fp32 output) ----------------
__global__ void head_kernel(const float* __restrict__ feat,
                            const void* __restrict__ W,
                            const void* __restrict__ bias,
                            float* __restrict__ out, int N, int off,
                            const int* __restrict__ dflag) {
    bool isb = (*dflag != 0);
    __shared__ float sf[DMODEL];
    int b = blockIdx.y;
    for (int i = threadIdx.x; i < DMODEL; i += 256) sf[i] = feat[b * DMODEL + i];
    __syncthreads();
    int j = blockIdx.x * 256 + threadIdx.x;
    if (j < N) {
        float acc = ldw(bias, j, isb);
        if (isb) {
            const bf16* Wb = (const bf16*)W;
            for (int k = 0; k < DMODEL; ++k)
                acc += sf[k] * __bfloat162float(Wb[(size_t)k * N + j]);
        } else {
            const float* Wf = (const float*)W;
            for (int k = 0; k < DMODEL; ++k)
                acc += sf[k] * Wf[(size_t)k * N + j];
        }
        out[(size_t)b * OUT_STRIDE + off + j] = acc;
    }
}

// ---------------------------------------------------------------------------
extern "C" void kernel_launch(void* const* d_in, const int* in_sizes, int n_in,
                              void* d_out, int out_size, void* d_ws, size_t ws_size,
                              hipStream_t stream) {
    const int*  tokens   = (const int*)d_in[0];
    const void* emb      = d_in[1];
    const void* ln_w     = d_in[2];
    const void* ln_b     = d_in[3];
    const void* in_proj  = d_in[4];
    const void* conv_w   = d_in[5];
    const void* conv_b   = d_in[6];
    const void* dt_bias  = d_in[7];
    const void* A_log    = d_in[8];
    const void* Dp       = d_in[9];
    const void* gnorm_w  = d_in[10];
    const void* out_proj = d_in[11];
    const void* normf_w  = d_in[12];
    const void* normf_b  = d_in[13];
    const void* pln_w    = d_in[14];
    const void* pln_b    = d_in[15];
    const void* order_w  = d_in[16];
    const void* order_b  = d_in[17];
    const void* family_w = d_in[18];
    const void* family_b = d_in[19];
    const void* genus_w  = d_in[20];
    const void* genus_b  = d_in[21];
    const void* species_w= d_in[22];
    const void* species_b= d_in[23];
    float* out = (float*)d_out;

    // fp32 workspace layout (~221 MB)
    float* ws    = (float*)d_ws;
    float* resid = ws;                                   // 16384*384
    float* hbuf  = resid + (size_t)ROWS * DMODEL;        // 16384*384 (dead
                                                         //  during scan ->
                                                         //  reused as Send)
    float* zx    = hbuf  + (size_t)ROWS * DMODEL;        // 16384*1680
    float* convb = zx    + (size_t)ROWS * DINPROJ;       // 16384*896
    float* dtb_  = convb + (size_t)ROWS * CONVDIM;       // 16384*16
    float* dAb   = dtb_  + (size_t)ROWS * NHEADS;        // 16384*16
    float* feat0 = dAb   + (size_t)ROWS * NHEADS;        // 32*384
    float* feat  = feat0 + (size_t)B_SZ * DMODEL;        // 32*384
    float* Pbuf  = feat  + (size_t)B_SZ * DMODEL;        // 2048
    int*   dflag = (int*)(Pbuf + 2048);

    detect_kernel<<<1, 1, 0, stream>>>(ln_w, dflag);
    embed_kernel<<<ROWS, DMODEL, 0, stream>>>(tokens, emb, resid, dflag);

    for (int l = 0; l < 2; ++l) {
        layernorm_off<<<ROWS, 64, 0, stream>>>(resid, ln_w, ln_b,
            (long)l * DMODEL, hbuf, DMODEL, dflag);
        // zxbcdt = h @ W_in   (16384 x 384 -> 1680)
        gemm_off<<<dim3((DINPROJ + 63) / 64, ROWS / 64), 256, 0, stream>>>(
            hbuf, DMODEL, in_proj, (long)l * DMODEL * DINPROJ,
            zx, DINPROJ, nullptr, ROWS, DINPROJ, DMODEL, dflag);
        conv_silu_off<<<dim3(7, ROWS), 128, 0, stream>>>(
            zx, conv_w, conv_b, (long)l * CONVDIM * 4, (long)l * CONVDIM,
            convb, dflag);
        dt_off<<<(ROWS * NHEADS) / 256, 256, 0, stream>>>(
            zx, dt_bias, A_log, (long)l * NHEADS, dtb_, dAb, dflag);
        // chunked parallel scan (hbuf reused as Send between in_proj and LN)
        scan_p1<<<B_SZ * NHEADS * NCH, 64, 0, stream>>>(convb, dtb_, dAb, hbuf, Pbuf);
        scan_p2<<<B_SZ * NHEADS, 64, 0, stream>>>(hbuf, Pbuf);
        scan_p3<<<B_SZ * NHEADS * NCH, 64, 0, stream>>>(convb, dtb_, dAb, Dp,
            (long)l * NHEADS, hbuf, dflag);
        gated_off<<<ROWS, 256, 0, stream>>>(convb, zx, gnorm_w,
            (long)l * DINNER, dflag);
        // resid += y @ W_out  (16384 x 768 -> 384), y rows strided by 896
        gemm_off<<<dim3(DMODEL / 64, ROWS / 64), 256, 0, stream>>>(
            convb, CONVDIM, out_proj, (long)l * DINNER * DMODEL,
            resid, DMODEL, resid, ROWS, DMODEL, DINNER, dflag);
    }

    layernorm_off<<<ROWS, 64, 0, stream>>>(resid, normf_w, normf_b, 0L,
                                           hbuf, DMODEL, dflag);
    pool_kernel<<<B_SZ, DMODEL, 0, stream>>>(hbuf, feat0);
    layernorm_off<<<B_SZ, 64, 0, stream>>>(feat0, pln_w, pln_b, 0L,
                                           feat, DMODEL, dflag);

    head_kernel<<<dim3(1, B_SZ), 256, 0, stream>>>(feat, order_w, order_b, out, 60, 0, dflag);
    head_kernel<<<dim3(2, B_SZ), 256, 0, stream>>>(feat, family_w, family_b, out, 427, 60, dflag);
    head_kernel<<<dim3(56, B_SZ), 256, 0, stream>>>(feat, genus_w, genus_b, out, 14216, 487, dflag);
    head_kernel<<<dim3(94, B_SZ), 256, 0, stream>>>(feat, species_w, species_b, out, 23964, 14703, dflag);
}

// Round 8
// 2005.170 us; speedup vs baseline: 1.5104x; 1.3206x over previous
//
#include <hip/hip_runtime.h>
#include <hip/hip_bf16.h>
#include <cmath>

// ---------------------------------------------------------------------------
// MultiHeadMamba6mer: 2-layer Mamba2 + 4 classification heads.
// B=32 L=512 D_MODEL=384 D_INNER=768 D_STATE=64 D_CONV=4 HEADDIM=48 NHEADS=16
// D_IN_PROJ=1680 CONV_DIM=896. Output (32, 38667) FLOAT32.
// Input float dtype AUTO-DETECTED (fp32 vs bf16) from ln_w (== ones).
// R7: chunked parallel scan (4 chunks, 3 phases): scan 1480 -> 360 us/p3.
// R8: (a) amdgpu_waves_per_eu(1,2) on scan kernels -- R7 showed VGPR=64 (st
//     in AGPRs, 5 ops/state-elem instead of 3) because the allocator aimed
//     for 4 waves/EU the grid never supplies. (b) GEMMs -> bf16 MFMA
//     (mfma_f32_16x16x32_bf16, 64x64 tile): inputs are bf16-valued, W
//     converts exactly; SIMT fp32 GEMMs were ~1280 us of the 2648 total.
// ---------------------------------------------------------------------------

#define B_SZ 32
#define L_SZ 512
#define DMODEL 384
#define DINNER 768
#define DSTATE 64
#define HEADDIM 48
#define NHEADS 16
#define DINPROJ 1680
#define CONVDIM 896
#define ROWS (B_SZ * L_SZ)          // 16384
#define OUT_STRIDE 38667
#define NCH 4                        // scan chunks
#define CHL (L_SZ / NCH)             // 128 timesteps per chunk
#define LDT 56                       // GEMM LDS row stride (bf16 units)

typedef __hip_bfloat16 bf16;
typedef __attribute__((ext_vector_type(8))) short bfrag;   // 8 bf16 (4 VGPRs)
typedef __attribute__((ext_vector_type(4))) float ffrag;   // 4 fp32 acc

__device__ __forceinline__ float ldw(const void* p, size_t i, bool isb) {
    if (isb) return __bfloat162float(((const bf16*)p)[i]);
    else     return ((const float*)p)[i];
}

// fp32 -> bf16 bits, round-to-nearest-even (exact for bf16-valued fp32).
__device__ __forceinline__ short f2bs(float f) {
    unsigned u = __float_as_uint(f);
    u = u + 0x7FFFu + ((u >> 16) & 1u);
    return (short)(u >> 16);
}

// ---------------- dtype detect: flag = 1 if bf16, 0 if fp32 ----------------
__global__ void detect_kernel(const void* __restrict__ ln_w, int* __restrict__ flag) {
    unsigned u = *(const unsigned*)ln_w;
    *flag = (u == 0x3F800000u) ? 0 : 1;
}

// ---------------- embed ----------------
__global__ void embed_kernel(const int* __restrict__ tok,
                             const void* __restrict__ emb,
                             float* __restrict__ resid,
                             const int* __restrict__ dflag) {
    bool isb = (*dflag != 0);
    int r = blockIdx.x, d = threadIdx.x;                  // block 384
    resid[(size_t)r * DMODEL + d] = ldw(emb, (size_t)tok[r] * DMODEL + d, isb);
}

// ---------------- layernorm (one wave per row) ----------------
__global__ void layernorm_off(const float* __restrict__ x,
                              const void* __restrict__ w,
                              const void* __restrict__ b, long off,
                              float* __restrict__ out, int D,
                              const int* __restrict__ dflag) {
    bool isb = (*dflag != 0);
    int row = blockIdx.x, lane = threadIdx.x;             // block 64
    const float* xr = x + (size_t)row * D;
    float s = 0.f, s2 = 0.f;
    for (int d = lane; d < D; d += 64) { float v = xr[d]; s += v; s2 += v * v; }
    #pragma unroll
    for (int o = 32; o; o >>= 1) { s += __shfl_xor(s, o); s2 += __shfl_xor(s2, o); }
    float mu = s / D;
    float var = s2 / D - mu * mu;
    float rinv = rsqrtf(var + 1e-5f);
    for (int d = lane; d < D; d += 64)
        out[(size_t)row * D + d] =
            (xr[d] - mu) * rinv * ldw(w, off + d, isb) + ldw(b, off + d, isb);
}

// ---------------- bf16 MFMA GEMM: C[M,N] = A[M,K](lda,fp32) * W[K,N] (+Cadd) --
// Block 256 (4 waves), tile 64x64, K-step 32. Wave w: rows w*16..w*16+15,
// 4 n-tiles. LDS rows stride LDT=56 bf16 (112B: 16B-aligned b128 frag reads,
// <=2-way bank aliasing). Frag layouts (verified, learn_hip m89/m120):
// A[m=lane&15][k=(lane>>4)*8+j], B[k=(lane>>4)*8+j][n=lane&15],
// D col=lane&15, row=(lane>>4)*4+reg.
__global__ __launch_bounds__(256)
void gemm_mfma(const float* __restrict__ A, int lda,
               const void* __restrict__ Bw, long boff,
               float* __restrict__ C, int ldc,
               const float* __restrict__ Cadd,
               int M, int N, int K,
               const int* __restrict__ dflag) {
    bool isb = (*dflag != 0);
    __shared__ short As[64 * LDT];
    __shared__ short Bs[64 * LDT];                        // Bs[n][k] (transposed)
    const int tid = threadIdx.x;
    const int lane = tid & 63;
    const int w = tid >> 6;
    const int bm = blockIdx.y * 64;
    const int bn = blockIdx.x * 64;
    ffrag acc[4];
    #pragma unroll
    for (int i = 0; i < 4; ++i) acc[i] = 0.f;

    for (int k0 = 0; k0 < K; k0 += 32) {
        // stage A: 64x32 fp32 -> bf16, float4 loads (2 quads/thread)
        #pragma unroll
        for (int i = 0; i < 2; ++i) {
            int e = tid + 256 * i;                        // 0..511 quads
            int m = e >> 3, kq = (e & 7) * 4;
            float4 v = *(const float4*)&A[(size_t)(bm + m) * lda + k0 + kq];
            short* d = &As[m * LDT + kq];
            d[0] = f2bs(v.x); d[1] = f2bs(v.y); d[2] = f2bs(v.z); d[3] = f2bs(v.w);
        }
        // stage B: 32x64 -> Bs[n][k] transposed (4 scalar writes/quad)
        #pragma unroll
        for (int i = 0; i < 2; ++i) {
            int e = tid + 256 * i;                        // 0..511 quads
            int k = e >> 4, n0 = (e & 15) * 4;
            #pragma unroll
            for (int j = 0; j < 4; ++j) {
                int gn = bn + n0 + j;
                float v = (gn < N) ? ldw(Bw, boff + (size_t)(k0 + k) * N + gn, isb) : 0.f;
                Bs[(n0 + j) * LDT + k] = f2bs(v);
            }
        }
        __syncthreads();
        int mrow = w * 16 + (lane & 15);
        int qoff = (lane >> 4) * 8;
        bfrag af = *(const bfrag*)&As[mrow * LDT + qoff];
        #pragma unroll
        for (int nt = 0; nt < 4; ++nt) {
            int ncol = nt * 16 + (lane & 15);
            bfrag bf = *(const bfrag*)&Bs[ncol * LDT + qoff];
            acc[nt] = __builtin_amdgcn_mfma_f32_16x16x32_bf16(af, bf, acc[nt], 0, 0, 0);
        }
        __syncthreads();
    }
    // epilogue
    int r0 = (lane >> 4) * 4;
    int col = lane & 15;
    #pragma unroll
    for (int nt = 0; nt < 4; ++nt) {
        int gn = bn + nt * 16 + col;
        if (gn < N) {
            #pragma unroll
            for (int r = 0; r < 4; ++r) {
                int gm = bm + w * 16 + r0 + r;
                size_t idx = (size_t)gm * ldc + gn;
                float v = acc[nt][r];
                if (Cadd) v += Cadd[idx];
                C[idx] = v;
            }
        }
    }
}

// ---------------- causal depthwise conv(4) + bias + SiLU ----------------
__global__ void conv_silu_off(const float* __restrict__ zx,
                              const void* __restrict__ cw,
                              const void* __restrict__ cb,
                              long cwoff, long cboff,
                              float* __restrict__ out,
                              const int* __restrict__ dflag) {
    bool isb = (*dflag != 0);
    int c = blockIdx.x * 128 + threadIdx.x;               // < 896 (7*128)
    int r = blockIdx.y;                                   // b*512 + l
    int l = r & (L_SZ - 1);
    float acc = ldw(cb, cboff + c, isb);
    #pragma unroll
    for (int k = 0; k < 4; ++k) {
        int lsrc = l + k - 3;
        if (lsrc >= 0)
            acc += zx[(size_t)(r + k - 3) * DINPROJ + DINNER + c] *
                   ldw(cw, cwoff + c * 4 + k, isb);
    }
    out[(size_t)r * CONVDIM + c] = acc / (1.f + expf(-acc));
}

// ---------------- dt = softplus(raw + bias); dA = exp(-exp(alog)*dt) ----------
__global__ void dt_off(const float* __restrict__ zx,
                       const void* __restrict__ dtb,
                       const void* __restrict__ alog, long hoff,
                       float* __restrict__ dtout, float* __restrict__ dAout,
                       const int* __restrict__ dflag) {
    bool isb = (*dflag != 0);
    int idx = blockIdx.x * 256 + threadIdx.x;             // < ROWS*NHEADS
    int r = idx >> 4, h = idx & 15;
    float x = zx[(size_t)r * DINPROJ + (DINPROJ - NHEADS) + h] + ldw(dtb, hoff + h, isb);
    float sp = (x > 20.f) ? x : log1pf(expf(x));
    float A = expf(ldw(alog, hoff + h, isb));
    dtout[idx] = sp;
    dAout[idx] = expf(-A * sp);
}

// ============ chunked parallel SSM scan ============
// Grid 2048 = (b, h, chunk); block = 1 wave. Lane p<48 holds state[p][0..63].
// waves_per_eu(1,2): grid supplies only 2 waves/EU -- let the allocator use
// 256 VGPRs so st[64] stays in VGPRs (R7: VGPR=64, st in AGPRs, 5 ops/elem).

// Phase 1: local scan from zero state; write S_end and P = prod(dA).
__attribute__((amdgpu_waves_per_eu(1, 2)))
__global__ __launch_bounds__(64)
void scan_p1(const float* __restrict__ conv,
             const float* __restrict__ dtg,
             const float* __restrict__ dAg,
             float* __restrict__ Send, float* __restrict__ Pbuf) {
    int c = blockIdx.x & (NCH - 1);
    int h = (blockIdx.x >> 2) & 15;
    int b = blockIdx.x >> 6;
    int lane = threadIdx.x;
    const float* base = conv + (size_t)b * L_SZ * CONVDIM;
    int t0 = c * CHL;
    size_t ri0 = ((size_t)(b * L_SZ + t0 + lane)) * NHEADS + h;
    size_t ri1 = ((size_t)(b * L_SZ + t0 + 64 + lane)) * NHEADS + h;
    float vdt0 = dtg[ri0], vdt1 = dtg[ri1];
    float vdA0 = dAg[ri0], vdA1 = dAg[ri1];
    float st[64];
    #pragma unroll
    for (int n = 0; n < 64; ++n) st[n] = 0.f;
    float aprod = 1.f;
    float xv_next = (lane < HEADDIM) ? base[(size_t)t0 * CONVDIM + h * HEADDIM + lane] : 0.f;
    for (int tt = 0; tt < CHL; ++tt) {
        int t = t0 + tt;
        float xv = xv_next;
        if (tt + 1 < CHL)
            xv_next = (lane < HEADDIM) ? base[(size_t)(t + 1) * CONVDIM + h * HEADDIM + lane] : 0.f;
        float dtv = __shfl(tt < 64 ? vdt0 : vdt1, tt & 63);
        float dAv = __shfl(tt < 64 ? vdA0 : vdA1, tt & 63);
        float coef = dtv * xv;
        aprod *= dAv;
        const float4* B4 = (const float4*)(base + (size_t)t * CONVDIM + DINNER);
        #pragma unroll
        for (int q = 0; q < 16; ++q) {
            float4 Bq = B4[q];                            // uniform address
            st[4*q + 0] = st[4*q + 0] * dAv + coef * Bq.x;
            st[4*q + 1] = st[4*q + 1] * dAv + coef * Bq.y;
            st[4*q + 2] = st[4*q + 2] * dAv + coef * Bq.z;
            st[4*q + 3] = st[4*q + 3] * dAv + coef * Bq.w;
        }
    }
    if (lane < HEADDIM) {
        float4* dst = (float4*)(Send + (size_t)blockIdx.x * 3072 + lane * 64);
        #pragma unroll
        for (int q = 0; q < 16; ++q)
            dst[q] = make_float4(st[4*q], st[4*q+1], st[4*q+2], st[4*q+3]);
    }
    if (lane == 0) Pbuf[blockIdx.x] = aprod;
}

// Phase 2: per (b,h): sequential prefix over chunks (elementwise, coalesced).
__global__ void scan_p2(float* __restrict__ Send, const float* __restrict__ Pbuf) {
    int bh = blockIdx.x;                                  // 512 blocks
    int lane = threadIdx.x;                               // 64
    float4 S[12];
    #pragma unroll
    for (int q = 0; q < 12; ++q) S[q] = make_float4(0.f, 0.f, 0.f, 0.f);
    for (int c = 0; c < NCH - 1; ++c) {
        float4* slot = (float4*)(Send + ((size_t)bh * NCH + c) * 3072);
        float P = Pbuf[bh * NCH + c];
        #pragma unroll
        for (int q = 0; q < 12; ++q) {
            float4 L = slot[lane + 64 * q];
            S[q].x = S[q].x * P + L.x;
            S[q].y = S[q].y * P + L.y;
            S[q].z = S[q].z * P + L.z;
            S[q].w = S[q].w * P + L.w;
            slot[lane + 64 * q] = S[q];
        }
    }
}

// Phase 3: re-run recurrence with injected prefix state; emit y in place.
__attribute__((amdgpu_waves_per_eu(1, 2)))
__global__ __launch_bounds__(64)
void scan_p3(float* __restrict__ conv,
             const float* __restrict__ dtg,
             const float* __restrict__ dAg,
             const void* __restrict__ Dsk, long hoff,
             const float* __restrict__ Send,
             const int* __restrict__ dflag) {
    bool isb = (*dflag != 0);
    int c = blockIdx.x & (NCH - 1);
    int h = (blockIdx.x >> 2) & 15;
    int b = blockIdx.x >> 6;
    int lane = threadIdx.x;
    float* base = conv + (size_t)b * L_SZ * CONVDIM;
    int t0 = c * CHL;
    size_t ri0 = ((size_t)(b * L_SZ + t0 + lane)) * NHEADS + h;
    size_t ri1 = ((size_t)(b * L_SZ + t0 + 64 + lane)) * NHEADS + h;
    float vdt0 = dtg[ri0], vdt1 = dtg[ri1];
    float vdA0 = dAg[ri0], vdA1 = dAg[ri1];
    float dskip = ldw(Dsk, hoff + h, isb);
    float st[64];
    if (c == 0) {
        #pragma unroll
        for (int n = 0; n < 64; ++n) st[n] = 0.f;
    } else {
        const float4* pre = (const float4*)(Send + ((size_t)blockIdx.x - 1) * 3072);
        if (lane < HEADDIM) {
            #pragma unroll
            for (int q = 0; q < 16; ++q) {
                float4 v = pre[lane * 16 + q];
                st[4*q] = v.x; st[4*q+1] = v.y; st[4*q+2] = v.z; st[4*q+3] = v.w;
            }
        } else {
            #pragma unroll
            for (int n = 0; n < 64; ++n) st[n] = 0.f;
        }
    }
    float xv_next = (lane < HEADDIM) ? base[(size_t)t0 * CONVDIM + h * HEADDIM + lane] : 0.f;
    for (int tt = 0; tt < CHL; ++tt) {
        int t = t0 + tt;
        float xv = xv_next;
        if (tt + 1 < CHL)
            xv_next = (lane < HEADDIM) ? base[(size_t)(t + 1) * CONVDIM + h * HEADDIM + lane] : 0.f;
        float dtv = __shfl(tt < 64 ? vdt0 : vdt1, tt & 63);
        float dAv = __shfl(tt < 64 ? vdA0 : vdA1, tt & 63);
        float coef = dtv * xv;
        const float4* B4 = (const float4*)(base + (size_t)t * CONVDIM + DINNER);
        const float4* C4 = (const float4*)(base + (size_t)t * CONVDIM + DINNER + DSTATE);
        float a0 = 0.f, a1 = 0.f, a2 = 0.f, a3 = 0.f;
        #pragma unroll
        for (int q = 0; q < 16; ++q) {
            float4 Bq = B4[q];
            float4 Cq = C4[q];
            st[4*q + 0] = st[4*q + 0] * dAv + coef * Bq.x; a0 += st[4*q + 0] * Cq.x;
            st[4*q + 1] = st[4*q + 1] * dAv + coef * Bq.y; a1 += st[4*q + 1] * Cq.y;
            st[4*q + 2] = st[4*q + 2] * dAv + coef * Bq.z; a2 += st[4*q + 2] * Cq.z;
            st[4*q + 3] = st[4*q + 3] * dAv + coef * Bq.w; a3 += st[4*q + 3] * Cq.w;
        }
        float y = (a0 + a1) + (a2 + a3) + dskip * xv;
        if (lane < HEADDIM)
            base[(size_t)t * CONVDIM + h * HEADDIM + lane] = y;
    }
}

// ---------------- gated RMSNorm ----------------
__global__ void gated_off(float* __restrict__ y,          // conv buf rows (896)
                          const float* __restrict__ zx,
                          const void* __restrict__ gw, long goff,
                          const int* __restrict__ dflag) {
    bool isb = (*dflag != 0);
    int row = blockIdx.x, tid = threadIdx.x;              // block 256
    float* yr = y + (size_t)row * CONVDIM;
    const float* zr = zx + (size_t)row * DINPROJ;
    float g[3], s2 = 0.f;
    #pragma unroll
    for (int i = 0; i < 3; ++i) {
        int d = tid + 256 * i;
        float z = zr[d];
        float sz = z / (1.f + expf(-z));
        float v = yr[d] * sz;
        g[i] = v; s2 += v * v;
    }
    #pragma unroll
    for (int o = 32; o; o >>= 1) s2 += __shfl_xor(s2, o);
    __shared__ float red[4];
    if ((tid & 63) == 0) red[tid >> 6] = s2;
    __syncthreads();
    s2 = red[0] + red[1] + red[2] + red[3];
    float rinv = rsqrtf(s2 / (float)DINNER + 1e-5f);
    #pragma unroll
    for (int i = 0; i < 3; ++i) {
        int d = tid + 256 * i;
        yr[d] = g[i] * rinv * ldw(gw, goff + d, isb);
    }
}

// ---------------- mean over L ----------------
__global__ void pool_kernel(const float* __restrict__ h, float* __restrict__ feat0) {
    int b = blockIdx.x, d = threadIdx.x;                  // block 384
    float s = 0.f;
    for (int l = 0; l < L_SZ; ++l) s += h[((size_t)b * L_SZ + l) * DMODEL + d];
    feat0[b * DMODEL + d] = s * (1.f / L_SZ);
}

// ---------------- head GEMV (fp32 output) ----------------
__global__ void head_kernel(const float* __restrict__ feat,
                            const void* __restrict__ W,
                            const void* __restrict__ bias,
                            float* __restrict__ out, int N, int off,
                            const int* __restrict__ dflag) {
    bool isb = (*dflag != 0);
    __shared__ float sf[DMODEL];
    int b = blockIdx.y;
    for (int i = threadIdx.x; i < DMODEL; i += 256) sf[i] = feat[b * DMODEL + i];
    __syncthreads();
    int j = blockIdx.x * 256 + threadIdx.x;
    if (j < N) {
        float acc = ldw(bias, j, isb);
        if (isb) {
            const bf16* Wb = (const bf16*)W;
            for (int k = 0; k < DMODEL; ++k)
                acc += sf[k] * __bfloat162float(Wb[(size_t)k * N + j]);
        } else {
            const float* Wf = (const float*)W;
            for (int k = 0; k < DMODEL; ++k)
                acc += sf[k] * Wf[(size_t)k * N + j];
        }
        out[(size_t)b * OUT_STRIDE + off + j] = acc;
    }
}

// ---------------------------------------------------------------------------
extern "C" void kernel_launch(void* const* d_in, const int* in_sizes, int n_in,
                              void* d_out, int out_size, void* d_ws, size_t ws_size,
                              hipStream_t stream) {
    const int*  tokens   = (const int*)d_in[0];
    const void* emb      = d_in[1];
    const void* ln_w     = d_in[2];
    const void* ln_b     = d_in[3];
    const void* in_proj  = d_in[4];
    const void* conv_w   = d_in[5];
    const void* conv_b   = d_in[6];
    const void* dt_bias  = d_in[7];
    const void* A_log    = d_in[8];
    const void* Dp       = d_in[9];
    const void* gnorm_w  = d_in[10];
    const void* out_proj = d_in[11];
    const void* normf_w  = d_in[12];
    const void* normf_b  = d_in[13];
    const void* pln_w    = d_in[14];
    const void* pln_b    = d_in[15];
    const void* order_w  = d_in[16];
    const void* order_b  = d_in[17];
    const void* family_w = d_in[18];
    const void* family_b = d_in[19];
    const void* genus_w  = d_in[20];
    const void* genus_b  = d_in[21];
    const void* species_w= d_in[22];
    const void* species_b= d_in[23];
    float* out = (float*)d_out;

    // fp32 workspace layout (~221 MB)
    float* ws    = (float*)d_ws;
    float* resid = ws;                                   // 16384*384
    float* hbuf  = resid + (size_t)ROWS * DMODEL;        // 16384*384 (dead
                                                         //  during scan ->
                                                         //  reused as Send)
    float* zx    = hbuf  + (size_t)ROWS * DMODEL;        // 16384*1680
    float* convb = zx    + (size_t)ROWS * DINPROJ;       // 16384*896
    float* dtb_  = convb + (size_t)ROWS * CONVDIM;       // 16384*16
    float* dAb   = dtb_  + (size_t)ROWS * NHEADS;        // 16384*16
    float* feat0 = dAb   + (size_t)ROWS * NHEADS;        // 32*384
    float* feat  = feat0 + (size_t)B_SZ * DMODEL;        // 32*384
    float* Pbuf  = feat  + (size_t)B_SZ * DMODEL;        // 2048
    int*   dflag = (int*)(Pbuf + 2048);

    detect_kernel<<<1, 1, 0, stream>>>(ln_w, dflag);
    embed_kernel<<<ROWS, DMODEL, 0, stream>>>(tokens, emb, resid, dflag);

    for (int l = 0; l < 2; ++l) {
        layernorm_off<<<ROWS, 64, 0, stream>>>(resid, ln_w, ln_b,
            (long)l * DMODEL, hbuf, DMODEL, dflag);
        // zxbcdt = h @ W_in   (16384 x 384 -> 1680), bf16 MFMA
        gemm_mfma<<<dim3((DINPROJ + 63) / 64, ROWS / 64), 256, 0, stream>>>(
            hbuf, DMODEL, in_proj, (long)l * DMODEL * DINPROJ,
            zx, DINPROJ, nullptr, ROWS, DINPROJ, DMODEL, dflag);
        conv_silu_off<<<dim3(7, ROWS), 128, 0, stream>>>(
            zx, conv_w, conv_b, (long)l * CONVDIM * 4, (long)l * CONVDIM,
            convb, dflag);
        dt_off<<<(ROWS * NHEADS) / 256, 256, 0, stream>>>(
            zx, dt_bias, A_log, (long)l * NHEADS, dtb_, dAb, dflag);
        // chunked parallel scan (hbuf reused as Send between in_proj and LN)
        scan_p1<<<B_SZ * NHEADS * NCH, 64, 0, stream>>>(convb, dtb_, dAb, hbuf, Pbuf);
        scan_p2<<<B_SZ * NHEADS, 64, 0, stream>>>(hbuf, Pbuf);
        scan_p3<<<B_SZ * NHEADS * NCH, 64, 0, stream>>>(convb, dtb_, dAb, Dp,
            (long)l * NHEADS, hbuf, dflag);
        gated_off<<<ROWS, 256, 0, stream>>>(convb, zx, gnorm_w,
            (long)l * DINNER, dflag);
        // resid += y @ W_out  (16384 x 768 -> 384), bf16 MFMA, fused resid add
        gemm_mfma<<<dim3(DMODEL / 64, ROWS / 64), 256, 0, stream>>>(
            convb, CONVDIM, out_proj, (long)l * DINNER * DMODEL,
            resid, DMODEL, resid, ROWS, DMODEL, DINNER, dflag);
    }

    layernorm_off<<<ROWS, 64, 0, stream>>>(resid, normf_w, normf_b, 0L,
                                           hbuf, DMODEL, dflag);
    pool_kernel<<<B_SZ, DMODEL, 0, stream>>>(hbuf, feat0);
    layernorm_off<<<B_SZ, 64, 0, stream>>>(feat0, pln_w, pln_b, 0L,
                                           feat, DMODEL, dflag);

    head_kernel<<<dim3(1, B_SZ), 256, 0, stream>>>(feat, order_w, order_b, out, 60, 0, dflag);
    head_kernel<<<dim3(2, B_SZ), 256, 0, stream>>>(feat, family_w, family_b, out, 427, 60, dflag);
    head_kernel<<<dim3(56, B_SZ), 256, 0, stream>>>(feat, genus_w, genus_b, out, 14216, 487, dflag);
    head_kernel<<<dim3(94, B_SZ), 256, 0, stream>>>(feat, species_w, species_b, out, 23964, 14703, dflag);
}